// Round 1
// baseline (468.139 us; speedup 1.0000x reference)
//
#include <hip/hip_runtime.h>
#include <cstdint>

// ---------------------------------------------------------------------------
// EncoderLayer (B=4, S=2048, D=768, H=12, FF=3072) on MI355X / gfx950.
// bf16 MFMA for all matmuls, flash-style attention, packed-bit mask.
// ---------------------------------------------------------------------------

typedef __bf16 bf16_t;
typedef __bf16 bf16x8 __attribute__((ext_vector_type(8)));
typedef float  f32x4  __attribute__((ext_vector_type(4)));

#define NEGF (-1e30f)

__device__ __forceinline__ f32x4 mfma16(bf16x8 a, bf16x8 b, f32x4 c) {
  return __builtin_amdgcn_mfma_f32_16x16x32_bf16(a, b, c, 0, 0, 0);
}

// global -> LDS direct 16B load. LDS dest must be wave-uniform-base + lane*16.
__device__ __forceinline__ void gload16(const bf16_t* gsrc, bf16_t* lds) {
  __builtin_amdgcn_global_load_lds(
      (const __attribute__((address_space(1))) unsigned int*)(uintptr_t)gsrc,
      (__attribute__((address_space(3))) unsigned int*)(uintptr_t)lds,
      16, 0, 0);
}

// ---------------------------------------------------------------------------
// Weight prep: Wt[n*K+k] = W[k*N+n] * scale, fp32 -> bf16
// ---------------------------------------------------------------------------
__global__ __launch_bounds__(256) void transpose_conv(
    const float* __restrict__ W, bf16_t* __restrict__ Wt, int K, int N, float scale)
{
  __shared__ float tile[32][33];
  const int n0 = blockIdx.x * 32, k0 = blockIdx.y * 32;
  const int tx = threadIdx.x, ty = threadIdx.y;
#pragma unroll
  for (int i = 0; i < 32; i += 8)
    tile[ty + i][tx] = W[(size_t)(k0 + ty + i) * N + n0 + tx];
  __syncthreads();
#pragma unroll
  for (int i = 0; i < 32; i += 8)
    Wt[(size_t)(n0 + ty + i) * K + k0 + tx] = (bf16_t)(tile[tx][ty + i] * scale);
}

// ---------------------------------------------------------------------------
// Mask pack: int32 [B,S,S] -> bits [B,S,S/32] (bit=1 means masked)
// ---------------------------------------------------------------------------
__global__ __launch_bounds__(256) void pack_mask(
    const int* __restrict__ mask, unsigned int* __restrict__ bits)
{
  const int gid = blockIdx.x * 256 + threadIdx.x;
  unsigned long long bal = __ballot(mask[gid] != 0);
  if ((threadIdx.x & 63) == 0) {
    const int wbase = gid >> 5;
    bits[wbase]     = (unsigned int)bal;
    bits[wbase + 1] = (unsigned int)(bal >> 32);
  }
}

// ---------------------------------------------------------------------------
// LayerNorm: fp32 [8192,768] -> bf16 [8192,768]
// ---------------------------------------------------------------------------
__global__ __launch_bounds__(256) void ln_kernel(
    const float* __restrict__ xin, const float* __restrict__ gamma,
    const float* __restrict__ beta, bf16_t* __restrict__ outb)
{
  __shared__ float red[8];
  const int row = blockIdx.x;
  const float* xr = xin + (size_t)row * 768;
  const int t = threadIdx.x;
  float v0 = xr[t], v1 = xr[t + 256], v2 = xr[t + 512];
  float s  = v0 + v1 + v2;
  float s2 = v0 * v0 + v1 * v1 + v2 * v2;
#pragma unroll
  for (int m = 32; m >= 1; m >>= 1) {
    s  += __shfl_xor(s, m, 64);
    s2 += __shfl_xor(s2, m, 64);
  }
  if ((t & 63) == 0) { red[t >> 6] = s; red[4 + (t >> 6)] = s2; }
  __syncthreads();
  s  = red[0] + red[1] + red[2] + red[3];
  s2 = red[4] + red[5] + red[6] + red[7];
  const float mu  = s * (1.0f / 768.0f);
  const float var = s2 * (1.0f / 768.0f) - mu * mu;
  const float rs  = rsqrtf(var + 1e-5f);
  bf16_t* orow = outb + (size_t)row * 768;
  orow[t]       = (bf16_t)((v0 - mu) * rs * gamma[t]       + beta[t]);
  orow[t + 256] = (bf16_t)((v1 - mu) * rs * gamma[t + 256] + beta[t + 256]);
  orow[t + 512] = (bf16_t)((v2 - mu) * rs * gamma[t + 512] + beta[t + 512]);
}

// ---------------------------------------------------------------------------
// GEMM: C[M,N] = A[M,K] @ Bt[N,K]^T  (A,Bt bf16 row-major)
// 128x128 tile, BK=32, 4 waves (each 64x64), global_load_lds staging.
// ---------------------------------------------------------------------------
template <bool RELU, bool OUT_F32, bool HAS_BIAS, bool HAS_RES>
__global__ __launch_bounds__(256) void gemm_kernel(
    const bf16_t* __restrict__ A, const bf16_t* __restrict__ Bt,
    void* __restrict__ Cout, const float* __restrict__ bias,
    const float* __restrict__ res, int Mdim, int Ndim, int Kdim)
{
  __shared__ __align__(16) bf16_t As[128 * 32];
  __shared__ __align__(16) bf16_t Bs[128 * 32];
  const int tid = threadIdx.x;
  const int lane = tid & 63, w = tid >> 6;
  const int l15 = lane & 15, g = lane >> 4;
  const int bm = blockIdx.y * 128, bn = blockIdx.x * 128;
  const int wr = (w >> 1) * 64, wc = (w & 1) * 64;

  f32x4 acc[4][4] = {};
  const int nK = Kdim >> 5;
  for (int kt = 0; kt < nK; ++kt) {
    const int k0 = kt << 5;
#pragma unroll
    for (int it = 0; it < 2; ++it) {
      const int ch = it * 256 + tid;       // 0..511 chunks of 8 bf16
      const int r = ch >> 2, cc = ch & 3;
      gload16(A  + (size_t)(bm + r) * Kdim + k0 + cc * 8, As + ch * 8);
      gload16(Bt + (size_t)(bn + r) * Kdim + k0 + cc * 8, Bs + ch * 8);
    }
    __syncthreads();
    bf16x8 af[4], bfr[4];
#pragma unroll
    for (int i = 0; i < 4; ++i)
      af[i] = *(const bf16x8*)(As + (wr + i * 16 + l15) * 32 + g * 8);
#pragma unroll
    for (int j = 0; j < 4; ++j)
      bfr[j] = *(const bf16x8*)(Bs + (wc + j * 16 + l15) * 32 + g * 8);
#pragma unroll
    for (int i = 0; i < 4; ++i)
#pragma unroll
      for (int j = 0; j < 4; ++j)
        acc[i][j] = mfma16(af[i], bfr[j], acc[i][j]);
    __syncthreads();
  }

#pragma unroll
  for (int i = 0; i < 4; ++i) {
#pragma unroll
    for (int j = 0; j < 4; ++j) {
      const int col = bn + wc + j * 16 + l15;
#pragma unroll
      for (int r = 0; r < 4; ++r) {
        const int row = bm + wr + i * 16 + g * 4 + r;
        float v = acc[i][j][r];
        if constexpr (HAS_BIAS) v += bias[col];
        if constexpr (HAS_RES)  v += res[(size_t)row * Ndim + col];
        if constexpr (RELU)     v = fmaxf(v, 0.f);
        if constexpr (OUT_F32)
          ((float*)Cout)[(size_t)row * Ndim + col] = v;
        else
          ((bf16_t*)Cout)[(size_t)row * Ndim + col] = (bf16_t)v;
      }
    }
  }
}

// ---------------------------------------------------------------------------
// V transpose: qkv v-columns [b*2048+s][1536+h*64+d] -> vT[(bh*64+d)][s]
// ---------------------------------------------------------------------------
__global__ __launch_bounds__(256) void transpose_v(
    const bf16_t* __restrict__ qkv, bf16_t* __restrict__ vT)
{
  __shared__ bf16_t t[64][66];
  const int st = blockIdx.x;       // s-tile of 64
  const int bh = blockIdx.y;       // 0..47
  const int b = bh / 12, h = bh % 12;
  const int tid = threadIdx.x;
#pragma unroll
  for (int it = 0; it < 2; ++it) {
    const int ch = it * 256 + tid;      // 0..511
    const int r = ch >> 3, c = ch & 7;  // r = s-row, c = d-chunk
    bf16x8 vv = *(const bf16x8*)(qkv + (size_t)(b * 2048 + st * 64 + r) * 2304 +
                                 1536 + h * 64 + c * 8);
#pragma unroll
    for (int j = 0; j < 8; ++j) t[r][c * 8 + j] = vv[j];
  }
  __syncthreads();
#pragma unroll
  for (int it = 0; it < 2; ++it) {
    const int ch = it * 256 + tid;
    const int d = ch >> 3, c = ch & 7;  // d-row, s-chunk
    bf16x8 o;
#pragma unroll
    for (int j = 0; j < 8; ++j) o[j] = t[c * 8 + j][d];
    *(bf16x8*)(vT + (size_t)(bh * 64 + d) * 2048 + st * 64 + c * 8) = o;
  }
}

// ---------------------------------------------------------------------------
// Flash attention. Block = (qt, bh), 256 thr / 4 waves, wave owns 32 q rows.
// Ks/Vs staged via gload16 with XOR-chunk swizzle (src pre-swizzled).
// ---------------------------------------------------------------------------
__global__ __launch_bounds__(256, 2) void attn_kernel(
    const bf16_t* __restrict__ qkv, const bf16_t* __restrict__ vT,
    const unsigned int* __restrict__ mbits, bf16_t* __restrict__ ctx)
{
  __shared__ __align__(16) bf16_t Ks[128 * 64];
  __shared__ __align__(16) bf16_t Vs[64 * 128];
  __shared__ __align__(16) bf16_t Ps[4][32 * 128];
  const int tid = threadIdx.x;
  const int lane = tid & 63, w = tid >> 6;
  const int l15 = lane & 15, g = lane >> 4;
  const int qt = blockIdx.x;      // 0..15
  const int bh = blockIdx.y;      // 0..47
  const int b = bh / 12, h = bh % 12;

  // ---- stage Q tile (swizzled) into Ks, load A-fragments, free Ks ----
  {
    const size_t qbase = (size_t)(b * 2048 + qt * 128);
#pragma unroll
    for (int it = 0; it < 4; ++it) {
      const int ch = it * 256 + tid;          // 0..1023
      const int r = ch >> 3, c = ch & 7;
      const int cs = c ^ (r & 7);
      gload16(qkv + (qbase + r) * 2304 + h * 64 + cs * 8, Ks + ch * 8);
    }
  }
  __syncthreads();
  bf16x8 qf[2][2];
#pragma unroll
  for (int i = 0; i < 2; ++i)
#pragma unroll
    for (int kk = 0; kk < 2; ++kk) {
      const int r = w * 32 + i * 16 + l15;
      qf[i][kk] = *(const bf16x8*)(Ks + r * 64 + ((kk * 4 + g) ^ (r & 7)) * 8);
    }
  __syncthreads();

  f32x4 oacc[2][4] = {};
  float mrun[2][4], lrun[2][4];
#pragma unroll
  for (int i = 0; i < 2; ++i)
#pragma unroll
    for (int r = 0; r < 4; ++r) { mrun[i][r] = NEGF; lrun[i][r] = 0.f; }

  for (int kt = 0; kt < 16; ++kt) {
    // ---- stage K tile [128 s][64 d] and V^T tile [64 d][128 s] ----
    const size_t kbase = (size_t)(b * 2048 + kt * 128);
#pragma unroll
    for (int it = 0; it < 4; ++it) {
      const int ch = it * 256 + tid;
      const int r = ch >> 3, c = ch & 7;
      const int cs = c ^ (r & 7);
      gload16(qkv + (kbase + r) * 2304 + 768 + h * 64 + cs * 8, Ks + ch * 8);
    }
#pragma unroll
    for (int it = 0; it < 4; ++it) {
      const int ch = it * 256 + tid;
      const int r = ch >> 4, c = ch & 15;
      const int cs = c ^ (r & 7);
      gload16(vT + (size_t)(bh * 64 + r) * 2048 + kt * 128 + cs * 8, Vs + ch * 8);
    }
    __syncthreads();

    // ---- QK^T: scores[2][8] = 32 q x 128 k per wave ----
    f32x4 sacc[2][8] = {};
#pragma unroll
    for (int j = 0; j < 8; ++j) {
      const int r = j * 16 + l15;
#pragma unroll
      for (int kk = 0; kk < 2; ++kk) {
        bf16x8 kfrag = *(const bf16x8*)(Ks + r * 64 + ((kk * 4 + g) ^ (r & 7)) * 8);
        sacc[0][j] = mfma16(qf[0][kk], kfrag, sacc[0][j]);
        sacc[1][j] = mfma16(qf[1][kk], kfrag, sacc[1][j]);
      }
    }

    // ---- mask + online softmax + write P (bf16, swizzled) ----
#pragma unroll
    for (int i = 0; i < 2; ++i) {
#pragma unroll
      for (int rr = 0; rr < 4; ++rr) {
        const int q = qt * 128 + w * 32 + i * 16 + g * 4 + rr;
        const uint4 mm = *(const uint4*)(mbits + (size_t)(b * 2048 + q) * 64 + kt * 4);
        const unsigned int mwa[4] = {mm.x, mm.y, mm.z, mm.w};
        float rmax = NEGF;
#pragma unroll
        for (int j = 0; j < 8; ++j) {
          const unsigned int wv = mwa[j >> 1];
          const bool msk = (wv >> ((j & 1) * 16 + l15)) & 1u;
          const float sv = msk ? NEGF : sacc[i][j][rr];
          sacc[i][j][rr] = sv;
          rmax = fmaxf(rmax, sv);
        }
#pragma unroll
        for (int m = 1; m < 16; m <<= 1) rmax = fmaxf(rmax, __shfl_xor(rmax, m, 64));
        const float mn = fmaxf(mrun[i][rr], rmax);
        const float sc = __expf(mrun[i][rr] - mn);
        float psum = 0.f;
#pragma unroll
        for (int j = 0; j < 8; ++j) {
          const float sv = sacc[i][j][rr];
          const float pv = (sv < -1e29f) ? 0.f : __expf(sv - mn);
          sacc[i][j][rr] = pv;
          psum += pv;
        }
#pragma unroll
        for (int m = 1; m < 16; m <<= 1) psum += __shfl_xor(psum, m, 64);
        mrun[i][rr] = mn;
        lrun[i][rr] = lrun[i][rr] * sc + psum;
#pragma unroll
        for (int jd = 0; jd < 4; ++jd) oacc[i][jd][rr] *= sc;
        const int rowp = i * 16 + g * 4 + rr;
#pragma unroll
        for (int j = 0; j < 8; ++j) {
          const int cc = (j * 2 + (l15 >> 3)) ^ (rowp & 7);
          Ps[w][rowp * 128 + cc * 8 + (l15 & 7)] = (bf16_t)sacc[i][j][rr];
        }
      }
    }
    __syncthreads();

    // ---- PV: O += P @ V ----
#pragma unroll
    for (int ks = 0; ks < 4; ++ks) {
      bf16x8 pa[2];
#pragma unroll
      for (int i = 0; i < 2; ++i) {
        const int rp = i * 16 + l15;
        pa[i] = *(const bf16x8*)(&Ps[w][rp * 128 + ((ks * 4 + g) ^ (rp & 7)) * 8]);
      }
#pragma unroll
      for (int jd = 0; jd < 4; ++jd) {
        const int rv = jd * 16 + l15;
        bf16x8 vb = *(const bf16x8*)(Vs + rv * 128 + ((ks * 4 + g) ^ (rv & 7)) * 8);
        oacc[0][jd] = mfma16(pa[0], vb, oacc[0][jd]);
        oacc[1][jd] = mfma16(pa[1], vb, oacc[1][jd]);
      }
    }
    __syncthreads();
  }

  // ---- normalize + write ctx [8192][768] ----
#pragma unroll
  for (int i = 0; i < 2; ++i)
#pragma unroll
    for (int rr = 0; rr < 4; ++rr) {
      const float l = lrun[i][rr];
      const float inv = (l > 0.f) ? 1.f / l : 0.f;
      const int q = qt * 128 + w * 32 + i * 16 + g * 4 + rr;
      bf16_t* crow = ctx + (size_t)(b * 2048 + q) * 768 + h * 64;
#pragma unroll
      for (int jd = 0; jd < 4; ++jd)
        crow[jd * 16 + l15] = (bf16_t)(oacc[i][jd][rr] * inv);
    }
}

// ---------------------------------------------------------------------------
// Host launcher
// ---------------------------------------------------------------------------
extern "C" void kernel_launch(void* const* d_in, const int* in_sizes, int n_in,
                              void* d_out, int out_size, void* d_ws, size_t ws_size,
                              hipStream_t stream) {
  const float* x  = (const float*)d_in[0];
  const int* mask = (const int*)d_in[1];
  const float* wq = (const float*)d_in[2];
  const float* wk = (const float*)d_in[3];
  const float* wv = (const float*)d_in[4];
  const float* wo = (const float*)d_in[5];
  const float* bo = (const float*)d_in[6];
  const float* w1 = (const float*)d_in[7];
  const float* w2 = (const float*)d_in[8];
  const float* g1 = (const float*)d_in[9];
  const float* b1 = (const float*)d_in[10];
  const float* g2 = (const float*)d_in[11];
  const float* b2 = (const float*)d_in[12];
  float* out = (float*)d_out;

  char* p = (char*)d_ws;
  bf16_t* WQKVT = (bf16_t*)p; p += (size_t)2304 * 768 * 2;
  bf16_t* WOT   = (bf16_t*)p; p += (size_t)768 * 768 * 2;
  bf16_t* W1T   = (bf16_t*)p; p += (size_t)3072 * 768 * 2;
  bf16_t* W2T   = (bf16_t*)p; p += (size_t)768 * 3072 * 2;
  unsigned int* MB = (unsigned int*)p; p += (size_t)4 * 2048 * 64 * 4;
  bf16_t* Hbuf  = (bf16_t*)p; p += (size_t)8192 * 768 * 2;
  float*  X2    = (float*)p;  p += (size_t)8192 * 768 * 4;
  bf16_t* QKV   = (bf16_t*)p; p += (size_t)8192 * 2304 * 2;
  bf16_t* CTX   = (bf16_t*)p;
  bf16_t* FFN   = QKV;    // overlays QKV+CTX (both dead by FFN1)
  bf16_t* VT    = Hbuf;   // overlays H (dead between QKV-GEMM and LN2)

  const dim3 tb(32, 8);
  // weight prep (wq carries the 1/sqrt(DH)=0.125 scale)
  transpose_conv<<<dim3(24, 24), tb, 0, stream>>>(wq, WQKVT,              768, 768, 0.125f);
  transpose_conv<<<dim3(24, 24), tb, 0, stream>>>(wk, WQKVT + 768 * 768,  768, 768, 1.f);
  transpose_conv<<<dim3(24, 24), tb, 0, stream>>>(wv, WQKVT + 1536 * 768, 768, 768, 1.f);
  transpose_conv<<<dim3(24, 24), tb, 0, stream>>>(wo, WOT, 768, 768, 1.f);
  transpose_conv<<<dim3(96, 24), tb, 0, stream>>>(w1, W1T, 768, 3072, 1.f);
  transpose_conv<<<dim3(24, 96), tb, 0, stream>>>(w2, W2T, 3072, 768, 1.f);
  pack_mask<<<65536, 256, 0, stream>>>(mask, MB);

  // attention sublayer
  ln_kernel<<<8192, 256, 0, stream>>>(x, g1, b1, Hbuf);
  gemm_kernel<false, false, false, false><<<dim3(18, 64), 256, 0, stream>>>(
      Hbuf, WQKVT, QKV, nullptr, nullptr, 8192, 2304, 768);
  transpose_v<<<dim3(32, 48), 256, 0, stream>>>(QKV, VT);
  attn_kernel<<<dim3(16, 48), 256, 0, stream>>>(QKV, VT, MB, CTX);
  gemm_kernel<false, true, true, true><<<dim3(6, 64), 256, 0, stream>>>(
      CTX, WOT, X2, bo, x, 8192, 768, 768);

  // FFN sublayer
  ln_kernel<<<8192, 256, 0, stream>>>(X2, g2, b2, Hbuf);
  gemm_kernel<true, false, false, false><<<dim3(24, 64), 256, 0, stream>>>(
      Hbuf, W1T, FFN, nullptr, nullptr, 8192, 3072, 768);
  gemm_kernel<false, true, false, true><<<dim3(6, 64), 256, 0, stream>>>(
      FFN, W2T, out, nullptr, X2, 8192, 768, 3072);
}